// Round 2
// baseline (336.859 us; speedup 1.0000x reference)
//
#include <hip/hip_runtime.h>

#define N_BATCH 256
#define SEQ     2048
#define L       50
#define CORE    58                  // output rows per block
#define HALO    3                   // iteration dependency radius
#define SP      72                  // p_s row stride in bf16 (144 B, 16B-aligned)
#define SB      72                  // B row stride in bf16
#define ITER    3

#define L2E 1.4426950408889634f
#define LN2 0.6931471805599453f

typedef __attribute__((ext_vector_type(8))) short bf16x8;
typedef __attribute__((ext_vector_type(4))) float f32x4;

__device__ __forceinline__ unsigned short f2b(float f) {
    unsigned int u = __builtin_bit_cast(unsigned int, f);
    u += 0x7FFFu + ((u >> 16) & 1u);            // RTNE
    return (unsigned short)(u >> 16);
}

// gfx950 packed f32->bf16 (RTNE)
__device__ __forceinline__ unsigned int cvt_pk_bf16(float lo, float hi) {
    unsigned int r;
    asm("v_cvt_pk_bf16_f32 %0, %1, %2" : "=v"(r) : "v"(lo), "v"(hi));
    return r;
}

template <int CTRL>
__device__ __forceinline__ float dpp_mov_f32(float x) {
    int xi = __builtin_bit_cast(int, x);
    int r  = __builtin_amdgcn_update_dpp(xi, xi, CTRL, 0xF, 0xF, false);
    return __builtin_bit_cast(float, r);
}

// 16-lane (nloc) sum entirely on the VALU:
// quad_perm xor1 (0xB1), xor2 (0x4E), then row_ror:4 (0x124) + row_ror:8 (0x128)
__device__ __forceinline__ float rowsum16(float s) {
    s += dpp_mov_f32<0xB1>(s);
    s += dpp_mov_f32<0x4E>(s);
    s += dpp_mov_f32<0x124>(s);
    s += dpp_mov_f32<0x128>(s);
    return s;
}

__device__ __forceinline__ float fexp2(float x) {
#if __has_builtin(__builtin_amdgcn_exp2f)
    return __builtin_amdgcn_exp2f(x);
#else
    return __expf(x * LN2);
#endif
}

// k-dim permutation: k' = (k&15)*4 + (k>>4). Applied to BOTH p writes and
// BL/BR staging -> contraction unchanged (bijection on k), but each lane's 4
// softmax outputs land contiguously -> one ds_write_b64, conflict-free.
#define KPERM(k) ((((k) & 15) << 2) | ((k) >> 4))

__global__ __attribute__((amdgpu_waves_per_eu(4, 8))) __launch_bounds__(256)
void mfvi_kernel(
    const float* __restrict__ unary,
    const float* __restrict__ mask,
    const float* __restrict__ trans,   // [L][L]
    const float* __restrict__ tstart,  // [L]
    const float* __restrict__ tend,    // [L]
    float* __restrict__ out)
{
    // Single 18432 B LDS pool, three successive lives:
    //  (a) B staging: BLs | BRs (9216 B each)
    //  (b) p double-buffer: buf0 | buf1 (9216 B each) -> ONE barrier per iter
    //  (c) fp32 out-stage (11600 B) for full-line coalesced stores
    __shared__ __attribute__((aligned(16))) unsigned short SH[2 * 64 * SB]; // 18432 B
    unsigned short* BLs = SH;               // BL[n][k'] = T[k][n]
    unsigned short* BRs = SH + 64 * SB;     // BR[n][k'] = T[n][k]
    float* stage = (float*)SH;

    const int tid   = threadIdx.x;
    const int lane  = tid & 63;
    const int wave  = tid >> 6;
    const int nloc  = lane & 15;
    const int quad  = lane >> 4;
    const int nb    = blockIdx.y;
    const int s0    = blockIdx.x * CORE;
    const int tile0 = s0 - HALO + wave * 16;   // global seq row of this wave's tile row 0

    // ---------- early global loads (in flight across LDS setup) ----------
    float uraw[4][4], mk[4], tsv[4], tev[4];
#pragma unroll
    for (int nt = 0; nt < 4; ++nt) {
        int c = nt * 16 + nloc;
        bool cl = c < L;
        tsv[nt] = cl ? tstart[c] : 0.f;
        tev[nt] = cl ? tend[c]   : 0.f;
    }
#pragma unroll
    for (int reg = 0; reg < 4; ++reg) {
        int g = tile0 + quad * 4 + reg;
        bool in = (unsigned)g < (unsigned)SEQ;
        mk[reg] = in ? mask[nb * SEQ + g] : 0.f;
#pragma unroll
        for (int nt = 0; nt < 4; ++nt) {
            int c = nt * 16 + nloc;
            bool cv = in && (c < L);
            uraw[nt][reg] = cv ? unary[((size_t)nb * SEQ + g) * L + c] : 0.f;
        }
    }

    // ---------- zero staging (pad rows/cols of BL/BR must be finite 0) ----------
    {
        uint2 z; z.x = 0u; z.y = 0u;
        uint2* p = (uint2*)SH;
        for (int i = tid; i < (2 * 64 * SB) / 4; i += 256) p[i] = z;
    }
    __syncthreads();

    // ---------- stage T: coalesced read, k-permuted LDS scatter ----------
    for (int i = tid; i < L * L; i += 256) {
        int r = i / L, c = i - r * L;
        unsigned short v = f2b(trans[i]);
        BLs[c * SB + KPERM(r)] = v;
        BRs[r * SB + KPERM(c)] = v;
    }
    __syncthreads();

    // ---------- B fragments -> registers (64 VGPRs, persistent) ----------
    bf16x8 bL[2][4], bR[2][4];
#pragma unroll
    for (int kk = 0; kk < 2; ++kk)
#pragma unroll
        for (int nt = 0; nt < 4; ++nt) {
            int off = (nt * 16 + nloc) * SB + kk * 32 + quad * 8;
            bL[kk][nt] = *(const bf16x8*)&BLs[off];
            bR[kk][nt] = *(const bf16x8*)&BRs[off];
        }
    __syncthreads();   // staging dead; p buffers live from here

    // ---------- q / umm in log2e domain ----------
    float q[4][4], umm[4][4];
#pragma unroll
    for (int reg = 0; reg < 4; ++reg) {
        int g = tile0 + quad * 4 + reg;
#pragma unroll
        for (int nt = 0; nt < 4; ++nt) {
            float bnd = (g == 0) ? tsv[nt] : tev[nt];   // already 0 for c>=L / OOR
            float qv  = uraw[nt][reg] * mk[reg];
            q[nt][reg]   = qv * L2E;
            umm[nt][reg] = (qv + bnd) * (mk[reg] * L2E);
        }
        mk[reg] *= L2E;   // epilogue scale: q' = umm' + mk'*acc
    }

    const int myrow = wave * 16 + quad * 4;
    int slL = wave * 16 + nloc - 1; if (slL < 0)  slL = 0;   // clamped -> don't-care rows
    int slR = wave * 16 + nloc + 1; if (slR > 63) slR = 63;
    const int pw_off  = myrow * SP + 4 * nloc;   // b64 write base (8B-aligned)
    const int paL_off = slL * SP + quad * 8;
    const int paR_off = slR * SP + quad * 8;
    const int grow0 = tile0 + quad * 4;

    // ---------- iterations: double-buffered p, ONE barrier per iteration ----------
    // 2-deep skew: a wave writing buf[(it+1)&1] can only coexist with a wave
    // still reading buf[it&1] -> disjoint buffers, no WAR hazard.
    for (int it = 0; it < ITER; ++it) {
        unsigned short* pbuf = SH + (it & 1) * (64 * SP);
        const bool v3 = (nloc < 2);                           // col 48+nloc < 50
#pragma unroll
        for (int reg = 0; reg < 4; ++reg) {
            float e0 = fexp2(q[0][reg]);
            float e1 = fexp2(q[1][reg]);
            float e2 = fexp2(q[2][reg]);
            float e3 = v3 ? fexp2(q[3][reg]) : 0.f;
            float s  = rowsum16(e0 + e1 + e2 + e3);
            int g = grow0 + reg;
            float inv = ((unsigned)g < (unsigned)SEQ) ? __builtin_amdgcn_rcpf(s) : 0.f;
            uint2 pk;
            pk.x = cvt_pk_bf16(e0 * inv, e1 * inv);
            pk.y = cvt_pk_bf16(e2 * inv, e3 * inv);
            *(uint2*)(pbuf + pw_off + reg * SP) = pk;         // ds_write_b64
        }
        __syncthreads();   // p[it] ready everywhere

        f32x4 acc[4];
#pragma unroll
        for (int nt = 0; nt < 4; ++nt) {
            acc[nt][0] = 0.f; acc[nt][1] = 0.f; acc[nt][2] = 0.f; acc[nt][3] = 0.f;
        }
#pragma unroll
        for (int kk = 0; kk < 2; ++kk) {
            bf16x8 aL = *(const bf16x8*)(pbuf + paL_off + kk * 32);
            bf16x8 aR = *(const bf16x8*)(pbuf + paR_off + kk * 32);
#pragma unroll
            for (int nt = 0; nt < 4; ++nt) {
                acc[nt] = __builtin_amdgcn_mfma_f32_16x16x32_bf16(aL, bL[kk][nt], acc[nt], 0, 0, 0);
                acc[nt] = __builtin_amdgcn_mfma_f32_16x16x32_bf16(aR, bR[kk][nt], acc[nt], 0, 0, 0);
            }
        }
        // no second barrier: next iteration targets the other buffer

#pragma unroll
        for (int reg = 0; reg < 4; ++reg)
#pragma unroll
            for (int nt = 0; nt < 4; ++nt)
                q[nt][reg] = umm[nt][reg] + mk[reg] * acc[nt][reg];
    }

    // ---------- staged store: pack [row][50] fp32 in LDS, full-line streaming copy ----------
    __syncthreads();   // all MFMA reads of SH done; safe to repurpose as stage
    const int gcnt = (SEQ - s0 < CORE) ? (SEQ - s0) : CORE;
#pragma unroll
    for (int reg = 0; reg < 4; ++reg) {
        int g = tile0 + quad * 4 + reg;
        if (g >= s0 && g < s0 + gcnt) {
#pragma unroll
            for (int nt = 0; nt < 4; ++nt) {
                int c = nt * 16 + nloc;
                if (c < L) stage[(g - s0) * L + c] = q[nt][reg] * LN2;
            }
        }
    }
    __syncthreads();
    {
        const int ocnt = gcnt * L;                                 // multiple of 4
        f32x4* dst = (f32x4*)(out + ((size_t)nb * SEQ + s0) * L);  // 16B-aligned
        const f32x4* src = (const f32x4*)stage;
        for (int i = tid; i < (ocnt >> 2); i += 256) dst[i] = src[i];
    }
}

extern "C" void kernel_launch(void* const* d_in, const int* in_sizes, int n_in,
                              void* d_out, int out_size, void* d_ws, size_t ws_size,
                              hipStream_t stream) {
    const float* unary  = (const float*)d_in[0];
    const float* mask   = (const float*)d_in[1];
    const float* trans  = (const float*)d_in[2];
    const float* tstart = (const float*)d_in[3];
    const float* tend   = (const float*)d_in[4];
    float* out = (float*)d_out;

    dim3 grid((SEQ + CORE - 1) / CORE, N_BATCH);   // 36 x 256
    mfvi_kernel<<<grid, dim3(256), 0, stream>>>(unary, mask, trans, tstart, tend, out);
}

// Round 3
// 230.015 us; speedup vs baseline: 1.4645x; 1.4645x over previous
//
#include <hip/hip_runtime.h>

#define N_BATCH 256
#define SEQ     2048
#define L       50
#define CORE    58                  // output rows per block
#define HALO    3                   // iteration dependency radius
#define SP      72                  // p_s row stride in bf16 (144 B, 16B-aligned)
#define SB      72                  // B row stride in bf16
#define ITER    3

#define L2E 1.4426950408889634f
#define LN2 0.6931471805599453f

typedef __attribute__((ext_vector_type(8))) short bf16x8;
typedef __attribute__((ext_vector_type(4))) float f32x4;

__device__ __forceinline__ unsigned short f2b(float f) {
    unsigned int u = __builtin_bit_cast(unsigned int, f);
    u += 0x7FFFu + ((u >> 16) & 1u);            // RTNE
    return (unsigned short)(u >> 16);
}

// gfx950 packed f32->bf16 (RTNE)
__device__ __forceinline__ unsigned int cvt_pk_bf16(float lo, float hi) {
    unsigned int r;
    asm("v_cvt_pk_bf16_f32 %0, %1, %2" : "=v"(r) : "v"(lo), "v"(hi));
    return r;
}

template <int CTRL>
__device__ __forceinline__ float dpp_mov_f32(float x) {
    int xi = __builtin_bit_cast(int, x);
    int r  = __builtin_amdgcn_update_dpp(xi, xi, CTRL, 0xF, 0xF, false);
    return __builtin_bit_cast(float, r);
}

// 16-lane (nloc) sum entirely on the VALU:
// quad_perm xor1 (0xB1), xor2 (0x4E), then row_ror:4 (0x124) + row_ror:8 (0x128)
__device__ __forceinline__ float rowsum16(float s) {
    s += dpp_mov_f32<0xB1>(s);
    s += dpp_mov_f32<0x4E>(s);
    s += dpp_mov_f32<0x124>(s);
    s += dpp_mov_f32<0x128>(s);
    return s;
}

__device__ __forceinline__ float fexp2(float x) {
#if __has_builtin(__builtin_amdgcn_exp2f)
    return __builtin_amdgcn_exp2f(x);
#else
    return __expf(x * LN2);
#endif
}

// k-dim permutation: k' = (k&15)*4 + (k>>4). Applied to BOTH p writes and
// BL/BR staging -> contraction unchanged (bijection on k), but each lane's 4
// softmax outputs land contiguously -> one ds_write_b64, conflict-free.
#define KPERM(k) ((((k) & 15) << 2) | ((k) >> 4))

// waves_per_eu PINNED (4,4): allocator budgets exactly 128 unified regs — the
// allocation round 1 achieved spill-free (64 arch VGPR + ~64 AGPR for the
// persistent B fragments). A (4,8) RANGE let the allocator gamble on 8
// waves/EU (64 regs) and spill the B-fragment file: +146 MB fetch / +368 MB
// write of scratch traffic in round 2. Never give this kernel a range.
__global__ __attribute__((amdgpu_waves_per_eu(4, 4))) __launch_bounds__(256)
void mfvi_kernel(
    const float* __restrict__ unary,
    const float* __restrict__ mask,
    const float* __restrict__ trans,   // [L][L]
    const float* __restrict__ tstart,  // [L]
    const float* __restrict__ tend,    // [L]
    float* __restrict__ out)
{
    // Single 18432 B LDS pool, three successive lives:
    //  (a) B staging: BLs | BRs (9216 B each)
    //  (b) p double-buffer: buf0 | buf1 (9216 B each) -> ONE barrier per iter
    //  (c) fp32 out-stage (11600 B) for full-line coalesced stores
    __shared__ __attribute__((aligned(16))) unsigned short SH[2 * 64 * SB]; // 18432 B
    unsigned short* BLs = SH;               // BL[n][k'] = T[k][n]
    unsigned short* BRs = SH + 64 * SB;     // BR[n][k'] = T[n][k]
    float* stage = (float*)SH;

    const int tid   = threadIdx.x;
    const int lane  = tid & 63;
    const int wave  = tid >> 6;
    const int nloc  = lane & 15;
    const int quad  = lane >> 4;
    const int nb    = blockIdx.y;
    const int s0    = blockIdx.x * CORE;
    const int tile0 = s0 - HALO + wave * 16;   // global seq row of this wave's tile row 0

    // ---------- early global loads (in flight across LDS setup) ----------
    float uraw[4][4], mk[4], tsv[4], tev[4];
#pragma unroll
    for (int nt = 0; nt < 4; ++nt) {
        int c = nt * 16 + nloc;
        bool cl = c < L;
        tsv[nt] = cl ? tstart[c] : 0.f;
        tev[nt] = cl ? tend[c]   : 0.f;
    }
#pragma unroll
    for (int reg = 0; reg < 4; ++reg) {
        int g = tile0 + quad * 4 + reg;
        bool in = (unsigned)g < (unsigned)SEQ;
        mk[reg] = in ? mask[nb * SEQ + g] : 0.f;
#pragma unroll
        for (int nt = 0; nt < 4; ++nt) {
            int c = nt * 16 + nloc;
            bool cv = in && (c < L);
            uraw[nt][reg] = cv ? unary[((size_t)nb * SEQ + g) * L + c] : 0.f;
        }
    }

    // ---------- zero staging (pad rows/cols of BL/BR must be finite 0) ----------
    {
        uint2 z; z.x = 0u; z.y = 0u;
        uint2* p = (uint2*)SH;
        for (int i = tid; i < (2 * 64 * SB) / 4; i += 256) p[i] = z;
    }
    __syncthreads();

    // ---------- stage T: coalesced read, k-permuted LDS scatter ----------
    for (int i = tid; i < L * L; i += 256) {
        int r = i / L, c = i - r * L;
        unsigned short v = f2b(trans[i]);
        BLs[c * SB + KPERM(r)] = v;
        BRs[r * SB + KPERM(c)] = v;
    }
    __syncthreads();

    // ---------- B fragments -> registers (64 VGPRs, persistent) ----------
    bf16x8 bL[2][4], bR[2][4];
#pragma unroll
    for (int kk = 0; kk < 2; ++kk)
#pragma unroll
        for (int nt = 0; nt < 4; ++nt) {
            int off = (nt * 16 + nloc) * SB + kk * 32 + quad * 8;
            bL[kk][nt] = *(const bf16x8*)&BLs[off];
            bR[kk][nt] = *(const bf16x8*)&BRs[off];
        }
    __syncthreads();   // staging dead; p buffers live from here

    // ---------- q / umm in log2e domain ----------
    float q[4][4], umm[4][4];
#pragma unroll
    for (int reg = 0; reg < 4; ++reg) {
        int g = tile0 + quad * 4 + reg;
#pragma unroll
        for (int nt = 0; nt < 4; ++nt) {
            float bnd = (g == 0) ? tsv[nt] : tev[nt];   // already 0 for c>=L / OOR
            float qv  = uraw[nt][reg] * mk[reg];
            q[nt][reg]   = qv * L2E;
            umm[nt][reg] = (qv + bnd) * (mk[reg] * L2E);
        }
        mk[reg] *= L2E;   // epilogue scale: q' = umm' + mk'*acc
    }

    const int myrow = wave * 16 + quad * 4;
    int slL = wave * 16 + nloc - 1; if (slL < 0)  slL = 0;   // clamped -> don't-care rows
    int slR = wave * 16 + nloc + 1; if (slR > 63) slR = 63;
    const int pw_off  = myrow * SP + 4 * nloc;   // b64 write base (8B-aligned)
    const int paL_off = slL * SP + quad * 8;
    const int paR_off = slR * SP + quad * 8;
    const int grow0 = tile0 + quad * 4;

    // ---------- iterations: double-buffered p, ONE barrier per iteration ----------
    // 2-deep skew: a wave writing buf[(it+1)&1] can only coexist with a wave
    // still reading buf[it&1] -> disjoint buffers, no WAR hazard.
    for (int it = 0; it < ITER; ++it) {
        unsigned short* pbuf = SH + (it & 1) * (64 * SP);
        const bool v3 = (nloc < 2);                           // col 48+nloc < 50
#pragma unroll
        for (int reg = 0; reg < 4; ++reg) {
            float e0 = fexp2(q[0][reg]);
            float e1 = fexp2(q[1][reg]);
            float e2 = fexp2(q[2][reg]);
            float e3 = v3 ? fexp2(q[3][reg]) : 0.f;
            float s  = rowsum16(e0 + e1 + e2 + e3);
            int g = grow0 + reg;
            float inv = ((unsigned)g < (unsigned)SEQ) ? __builtin_amdgcn_rcpf(s) : 0.f;
            uint2 pk;
            pk.x = cvt_pk_bf16(e0 * inv, e1 * inv);
            pk.y = cvt_pk_bf16(e2 * inv, e3 * inv);
            *(uint2*)(pbuf + pw_off + reg * SP) = pk;         // ds_write_b64
        }
        __syncthreads();   // p[it] ready everywhere

        f32x4 acc[4];
#pragma unroll
        for (int nt = 0; nt < 4; ++nt) {
            acc[nt][0] = 0.f; acc[nt][1] = 0.f; acc[nt][2] = 0.f; acc[nt][3] = 0.f;
        }
#pragma unroll
        for (int kk = 0; kk < 2; ++kk) {
            bf16x8 aL = *(const bf16x8*)(pbuf + paL_off + kk * 32);
            bf16x8 aR = *(const bf16x8*)(pbuf + paR_off + kk * 32);
#pragma unroll
            for (int nt = 0; nt < 4; ++nt) {
                acc[nt] = __builtin_amdgcn_mfma_f32_16x16x32_bf16(aL, bL[kk][nt], acc[nt], 0, 0, 0);
                acc[nt] = __builtin_amdgcn_mfma_f32_16x16x32_bf16(aR, bR[kk][nt], acc[nt], 0, 0, 0);
            }
        }
        // no second barrier: next iteration targets the other buffer

#pragma unroll
        for (int reg = 0; reg < 4; ++reg)
#pragma unroll
            for (int nt = 0; nt < 4; ++nt)
                q[nt][reg] = umm[nt][reg] + mk[reg] * acc[nt][reg];
    }

    // ---------- staged store: pack [row][50] fp32 in LDS, full-line streaming copy ----------
    __syncthreads();   // all MFMA reads of SH done; safe to repurpose as stage
    const int gcnt = (SEQ - s0 < CORE) ? (SEQ - s0) : CORE;
#pragma unroll
    for (int reg = 0; reg < 4; ++reg) {
        int g = tile0 + quad * 4 + reg;
        if (g >= s0 && g < s0 + gcnt) {
#pragma unroll
            for (int nt = 0; nt < 4; ++nt) {
                int c = nt * 16 + nloc;
                if (c < L) stage[(g - s0) * L + c] = q[nt][reg] * LN2;
            }
        }
    }
    __syncthreads();
    {
        const int ocnt = gcnt * L;                                 // multiple of 4
        f32x4* dst = (f32x4*)(out + ((size_t)nb * SEQ + s0) * L);  // 16B-aligned
        const f32x4* src = (const f32x4*)stage;
        for (int i = tid; i < (ocnt >> 2); i += 256) dst[i] = src[i];
    }
}

extern "C" void kernel_launch(void* const* d_in, const int* in_sizes, int n_in,
                              void* d_out, int out_size, void* d_ws, size_t ws_size,
                              hipStream_t stream) {
    const float* unary  = (const float*)d_in[0];
    const float* mask   = (const float*)d_in[1];
    const float* trans  = (const float*)d_in[2];
    const float* tstart = (const float*)d_in[3];
    const float* tend   = (const float*)d_in[4];
    float* out = (float*)d_out;

    dim3 grid((SEQ + CORE - 1) / CORE, N_BATCH);   // 36 x 256
    mfvi_kernel<<<grid, dim3(256), 0, stream>>>(unary, mask, trans, tstart, tend, out);
}

// Round 4
// 224.231 us; speedup vs baseline: 1.5023x; 1.0258x over previous
//
#include <hip/hip_runtime.h>

#define N_BATCH 256
#define SEQ     2048
#define L       50
#define CORE    58                  // output rows per block
#define HALO    3                   // iteration dependency radius
#define SP      72                  // p_s row stride in bf16 (144 B, 16B-aligned)
#define SB      72                  // B row stride in bf16
#define ITER    3

#define L2E 1.4426950408889634f
#define LN2 0.6931471805599453f

typedef __attribute__((ext_vector_type(8))) short bf16x8;
typedef __attribute__((ext_vector_type(4))) float f32x4;

__device__ __forceinline__ unsigned short f2b(float f) {
    unsigned int u = __builtin_bit_cast(unsigned int, f);
    u += 0x7FFFu + ((u >> 16) & 1u);            // RTNE
    return (unsigned short)(u >> 16);
}

// gfx950 packed f32->bf16 (RTNE)
__device__ __forceinline__ unsigned int cvt_pk_bf16(float lo, float hi) {
    unsigned int r;
    asm("v_cvt_pk_bf16_f32 %0, %1, %2" : "=v"(r) : "v"(lo), "v"(hi));
    return r;
}

template <int CTRL>
__device__ __forceinline__ float dpp_mov_f32(float x) {
    int xi = __builtin_bit_cast(int, x);
    int r  = __builtin_amdgcn_update_dpp(xi, xi, CTRL, 0xF, 0xF, false);
    return __builtin_bit_cast(float, r);
}

// 16-lane (nloc) sum entirely on the VALU:
// quad_perm xor1 (0xB1), xor2 (0x4E), then row_ror:4 (0x124) + row_ror:8 (0x128)
__device__ __forceinline__ float rowsum16(float s) {
    s += dpp_mov_f32<0xB1>(s);
    s += dpp_mov_f32<0x4E>(s);
    s += dpp_mov_f32<0x124>(s);
    s += dpp_mov_f32<0x128>(s);
    return s;
}

__device__ __forceinline__ float fexp2(float x) {
#if __has_builtin(__builtin_amdgcn_exp2f)
    return __builtin_amdgcn_exp2f(x);
#else
    return __expf(x * LN2);
#endif
}

// softmax of one 50-wide row slice (log2e domain) + normalized bf16 pack +
// single conflict-free ds_write_b64. x0..x3 are this lane's 4 elements
// (cols nloc, 16+nloc, 32+nloc, 48+nloc); v3 masks cols >= 50.
__device__ __forceinline__ void softmax_row_write(
    float x0, float x1, float x2, float x3, bool v3, bool valid,
    unsigned short* dst)
{
    float e0 = fexp2(x0);
    float e1 = fexp2(x1);
    float e2 = fexp2(x2);
    float e3 = v3 ? fexp2(x3) : 0.f;
    float s  = rowsum16(e0 + e1 + e2 + e3);
    float inv = valid ? __builtin_amdgcn_rcpf(s) : 0.f;   // 0 -> OOR rows give p=0
    uint2 pk;
    pk.x = cvt_pk_bf16(e0 * inv, e1 * inv);
    pk.y = cvt_pk_bf16(e2 * inv, e3 * inv);
    *(uint2*)dst = pk;
}

// k-dim permutation: k' = (k&15)*4 + (k>>4). Applied to BOTH p writes and
// BL/BR staging -> contraction unchanged (bijection on k), but each lane's 4
// softmax outputs land contiguously -> one ds_write_b64, conflict-free.
#define KPERM(k) ((((k) & 15) << 2) | ((k) >> 4))

// waves_per_eu PINNED (4,4): allocator budgets exactly 128 unified regs.
// A (4,8) RANGE let the allocator gamble on 8 waves/EU and spill the
// B-fragment file (round 2: +146 MB fetch / +368 MB write of scratch).
// Round 3 still spilled ~1 vec-reg/lane (peak ~130 > 128, WRITE +35 MB);
// round 4's fused softmax drops q[4][4] from the live set -> peak ~114.
__global__ __attribute__((amdgpu_waves_per_eu(4, 4))) __launch_bounds__(256)
void mfvi_kernel(
    const float* __restrict__ unary,
    const float* __restrict__ mask,
    const float* __restrict__ trans,   // [L][L]
    const float* __restrict__ tstart,  // [L]
    const float* __restrict__ tend,    // [L]
    float* __restrict__ out)
{
    // Single 18432 B LDS pool, three successive lives:
    //  (a) B staging: BLs | BRs (9216 B each)
    //  (b) p double-buffer: buf0 | buf1 (9216 B each) -> ONE barrier per iter
    //  (c) fp32 out-stage (11600 B) for full-line coalesced stores
    __shared__ __attribute__((aligned(16))) unsigned short SH[2 * 64 * SB]; // 18432 B
    unsigned short* BLs = SH;               // BL[n][k'] = T[k][n]
    unsigned short* BRs = SH + 64 * SB;     // BR[n][k'] = T[n][k]
    float* stage = (float*)SH;

    const int tid   = threadIdx.x;
    const int lane  = tid & 63;
    const int wave  = tid >> 6;
    const int nloc  = lane & 15;
    const int quad  = lane >> 4;
    const int nb    = blockIdx.y;
    const int s0    = blockIdx.x * CORE;
    const int tile0 = s0 - HALO + wave * 16;   // global seq row of this wave's tile row 0

    // ---------- early global loads (in flight across LDS setup) ----------
    float uraw[4][4], mk[4], tev[4];
#pragma unroll
    for (int nt = 0; nt < 4; ++nt) {
        int c = nt * 16 + nloc;
        tev[nt] = (c < L) ? tend[c] : 0.f;
    }
#pragma unroll
    for (int reg = 0; reg < 4; ++reg) {
        int g = tile0 + quad * 4 + reg;
        bool in = (unsigned)g < (unsigned)SEQ;
        mk[reg] = in ? mask[nb * SEQ + g] : 0.f;
#pragma unroll
        for (int nt = 0; nt < 4; ++nt) {
            int c = nt * 16 + nloc;
            bool cv = in && (c < L);
            uraw[nt][reg] = cv ? unary[((size_t)nb * SEQ + g) * L + c] : 0.f;
        }
    }

    // ---------- zero staging (pad rows/cols of BL/BR must be finite 0) ----------
    {
        uint4 z; z.x = 0u; z.y = 0u; z.z = 0u; z.w = 0u;
        uint4* p = (uint4*)SH;
        for (int i = tid; i < (2 * 64 * SB) / 8; i += 256) p[i] = z;
    }
    __syncthreads();

    // ---------- stage T: coalesced read, k-permuted LDS scatter ----------
    for (int i = tid; i < L * L; i += 256) {
        int r = i / L, c = i - r * L;
        unsigned short v = f2b(trans[i]);
        BLs[c * SB + KPERM(r)] = v;
        BRs[r * SB + KPERM(c)] = v;
    }
    __syncthreads();

    // ---------- B fragments -> registers (64 VGPRs, persistent) ----------
    bf16x8 bL[2][4], bR[2][4];
#pragma unroll
    for (int kk = 0; kk < 2; ++kk)
#pragma unroll
        for (int nt = 0; nt < 4; ++nt) {
            int off = (nt * 16 + nloc) * SB + kk * 32 + quad * 8;
            bL[kk][nt] = *(const bf16x8*)&BLs[off];
            bR[kk][nt] = *(const bf16x8*)&BRs[off];
        }
    __syncthreads();   // staging dead; p buffers live from here

    // ---------- umm (log2e domain) + initial q in-place in uraw ----------
    // q' = q*log2e; softmax(q) == 2^q' normalized; final out = q'_final * ln2.
    float umm[4][4];
#pragma unroll
    for (int reg = 0; reg < 4; ++reg) {
        int g = tile0 + quad * 4 + reg;
#pragma unroll
        for (int nt = 0; nt < 4; ++nt) {
            float bnd = tev[nt];
            if (g == 0) {                      // exactly one row in the whole grid
                int c = nt * 16 + nloc;
                bnd = (c < L) ? tstart[c] : 0.f;
            }
            float qv  = uraw[nt][reg] * mk[reg];
            uraw[nt][reg] = qv * L2E;                    // q'_init
            umm[nt][reg]  = (qv + bnd) * (mk[reg] * L2E);
        }
        mk[reg] *= L2E;   // fused scale: softmax input = umm' + mk'*acc
    }

    const int myrow = wave * 16 + quad * 4;
    int slL = wave * 16 + nloc - 1; if (slL < 0)  slL = 0;   // clamped -> don't-care rows
    int slR = wave * 16 + nloc + 1; if (slR > 63) slR = 63;
    const int pw_off  = myrow * SP + 4 * nloc;   // b64 write base (8B-aligned)
    const int paL_off = slL * SP + quad * 8;
    const int paR_off = slR * SP + quad * 8;
    const int grow0 = tile0 + quad * 4;
    const bool v3 = (nloc < 2);                  // col 48+nloc < 50

    // ---------- prologue: softmax#1 from q'_init, write p0 ----------
#pragma unroll
    for (int reg = 0; reg < 4; ++reg) {
        bool valid = (unsigned)(grow0 + reg) < (unsigned)SEQ;
        softmax_row_write(uraw[0][reg], uraw[1][reg], uraw[2][reg], uraw[3][reg],
                          v3, valid, SH + pw_off + reg * SP);
    }
    __syncthreads();   // p0 ready

    // ---------- iterations: MFMA then fused epilogue+softmax into p[next] ----------
    // 2-deep skew: a wave writing buf[(it+1)&1] can only coexist with a wave
    // still reading buf[it&1] -> disjoint buffers, no WAR hazard.
    f32x4 acc[4];
    for (int it = 0; it < ITER; ++it) {
        unsigned short* pbuf = SH + (it & 1) * (64 * SP);
#pragma unroll
        for (int nt = 0; nt < 4; ++nt) {
            acc[nt][0] = 0.f; acc[nt][1] = 0.f; acc[nt][2] = 0.f; acc[nt][3] = 0.f;
        }
#pragma unroll
        for (int kk = 0; kk < 2; ++kk) {
            bf16x8 aL = *(const bf16x8*)(pbuf + paL_off + kk * 32);
            bf16x8 aR = *(const bf16x8*)(pbuf + paR_off + kk * 32);
#pragma unroll
            for (int nt = 0; nt < 4; ++nt) {
                acc[nt] = __builtin_amdgcn_mfma_f32_16x16x32_bf16(aL, bL[kk][nt], acc[nt], 0, 0, 0);
                acc[nt] = __builtin_amdgcn_mfma_f32_16x16x32_bf16(aR, bR[kk][nt], acc[nt], 0, 0, 0);
            }
        }
        if (it < ITER - 1) {
            // fused epilogue+softmax: e = 2^(umm' + mk'*acc), no q[] live set
            unsigned short* nbuf = SH + ((it + 1) & 1) * (64 * SP);
#pragma unroll
            for (int reg = 0; reg < 4; ++reg) {
                bool valid = (unsigned)(grow0 + reg) < (unsigned)SEQ;
                softmax_row_write(umm[0][reg] + mk[reg] * acc[0][reg],
                                  umm[1][reg] + mk[reg] * acc[1][reg],
                                  umm[2][reg] + mk[reg] * acc[2][reg],
                                  umm[3][reg] + mk[reg] * acc[3][reg],
                                  v3, valid, nbuf + pw_off + reg * SP);
            }
            __syncthreads();   // p[it+1] ready; MFMA(it) reads all done block-wide
        }
    }

    // ---------- staged store: pack [row][50] fp32 in LDS, full-line streaming copy ----------
    __syncthreads();   // all MFMA reads of SH done; safe to repurpose as stage
    const int gcnt = (SEQ - s0 < CORE) ? (SEQ - s0) : CORE;
#pragma unroll
    for (int reg = 0; reg < 4; ++reg) {
        int g = tile0 + quad * 4 + reg;
        if (g >= s0 && g < s0 + gcnt) {
#pragma unroll
            for (int nt = 0; nt < 4; ++nt) {
                int c = nt * 16 + nloc;
                if (c < L)
                    stage[(g - s0) * L + c] = (umm[nt][reg] + mk[reg] * acc[nt][reg]) * LN2;
            }
        }
    }
    __syncthreads();
    {
        const int ocnt = gcnt * L;                                 // multiple of 4
        f32x4* dst = (f32x4*)(out + ((size_t)nb * SEQ + s0) * L);  // 16B-aligned
        const f32x4* src = (const f32x4*)stage;
        for (int i = tid; i < (ocnt >> 2); i += 256) dst[i] = src[i];
    }
}

extern "C" void kernel_launch(void* const* d_in, const int* in_sizes, int n_in,
                              void* d_out, int out_size, void* d_ws, size_t ws_size,
                              hipStream_t stream) {
    const float* unary  = (const float*)d_in[0];
    const float* mask   = (const float*)d_in[1];
    const float* trans  = (const float*)d_in[2];
    const float* tstart = (const float*)d_in[3];
    const float* tend   = (const float*)d_in[4];
    float* out = (float*)d_out;

    dim3 grid((SEQ + CORE - 1) / CORE, N_BATCH);   // 36 x 256
    mfvi_kernel<<<grid, dim3(256), 0, stream>>>(unary, mask, trans, tstart, tend, out);
}